// Round 6
// baseline (1913.622 us; speedup 1.0000x reference)
//
#include <hip/hip_runtime.h>

// ---------------------------------------------------------------------------
// MutualRec forward: 5x GATv2 + ChebConv(k=3) + mutualistic MLP + edge dots
// R5->R6: GEMM redesign "lane=row": X streamed via vector loads (float4),
//   acc[64] in VGPRs, W rows fetched per-k as wave-uniform scalar loads
//   (K$-resident, reused across stripes). No LDS, no barriers.
//   CSR-grouped GAT/ahat kernels (atomic-free) unchanged from R5.
// ---------------------------------------------------------------------------

#define LRELU_SLOPE 0.2f
#define EDGE_BLOCKS 2048

// ============================ GEMM family ==================================
// Y[N,64] = sum_m X_m[N,64] @ W[m] + b ; W is [NMAT*64,64] row-major stacked.
// lane = output row within a 64-row stripe; acc[64] = full output row.
template <int NMAT>
__global__ void gemm_rowlane_k(const float* __restrict__ X0,
                               const float* __restrict__ X1,
                               const float* __restrict__ X2,
                               const float* __restrict__ W,
                               const float* __restrict__ b,
                               float* __restrict__ Y, int N) {
  const int lane = threadIdx.x & 63;
  const int gw = (blockIdx.x * blockDim.x + threadIdx.x) >> 6;
  const int nw = (gridDim.x * blockDim.x) >> 6;
  const int nstripe = (N + 63) >> 6;
  for (int st = gw; st < nstripe; st += nw) {
    const int row = st * 64 + lane;
    const int rowc = row < N ? row : N - 1;   // clamp loads; store predicated
    float acc[64];
#pragma unroll
    for (int j = 0; j < 64; ++j) acc[j] = 0.0f;
#pragma unroll
    for (int m = 0; m < NMAT; ++m) {
      const float* Xm = (m == 0) ? X0 : ((m == 1) ? X1 : X2);
      const float* xr = Xm + (size_t)rowc * 64;
      const float* wm = W + m * 4096;
      float4 xc = *(const float4*)xr;         // chunk kc=0
#pragma unroll 1
      for (int kc = 0; kc < 16; ++kc) {
        const int kn = kc + 1 < 16 ? kc + 1 : 15;
        const float4 xn = *(const float4*)(xr + kn * 4);   // prefetch next
        const float* wr = wm + kc * 4 * 64;
#pragma unroll
        for (int kk = 0; kk < 4; ++kk) {
          const float xv = (kk == 0) ? xc.x : (kk == 1) ? xc.y
                         : (kk == 2) ? xc.z : xc.w;
          const float* wkr = wr + kk * 64;    // wave-uniform -> s_load
#pragma unroll
          for (int j = 0; j < 64; ++j)
            acc[j] = fmaf(xv, wkr[j], acc[j]);
        }
        xc = xn;
      }
    }
    if (row < N) {
      float* yr = Y + (size_t)row * 64;
#pragma unroll
      for (int jq = 0; jq < 16; ++jq) {
        float4 v;
        v.x = acc[jq * 4 + 0] + b[jq * 4 + 0];
        v.y = acc[jq * 4 + 1] + b[jq * 4 + 1];
        v.z = acc[jq * 4 + 2] + b[jq * 4 + 2];
        v.w = acc[jq * 4 + 3] + b[jq * 4 + 3];
        *(float4*)(yr + jq * 4) = v;
      }
    }
  }
}

static inline int gemm_grid(int N) {
  const int nstripe = (N + 63) >> 6;
  int blocks = (nstripe + 3) / 4;   // 4 waves per block, 1 stripe per wave
  if (blocks < 1) blocks = 1;
  if (blocks > 4096) blocks = 4096;
  return blocks;
}

// ========================= CSR build (counting sort) =======================
__global__ void hist_k(const int* __restrict__ key, int* __restrict__ cnt, int E) {
  const int e = blockIdx.x * blockDim.x + threadIdx.x;
  if (e < E) atomicAdd(cnt + key[e], 1);
}

// exclusive scan, 1024 elements per block (256 thr x 4)
__global__ void scan1_k(const int* __restrict__ in, int* __restrict__ out,
                        int* __restrict__ bsum, int n) {
  __shared__ int tmp[256];
  const int t = threadIdx.x;
  const int base = blockIdx.x * 1024 + t * 4;
  int v0 = (base + 0 < n) ? in[base + 0] : 0;
  int v1 = (base + 1 < n) ? in[base + 1] : 0;
  int v2 = (base + 2 < n) ? in[base + 2] : 0;
  int v3 = (base + 3 < n) ? in[base + 3] : 0;
  const int s = v0 + v1 + v2 + v3;
  tmp[t] = s;
  __syncthreads();
  for (int off = 1; off < 256; off <<= 1) {
    const int x = (t >= off) ? tmp[t - off] : 0;
    __syncthreads();
    tmp[t] += x;
    __syncthreads();
  }
  const int excl = tmp[t] - s;
  if (t == 255) bsum[blockIdx.x] = tmp[255];
  if (base + 0 < n) out[base + 0] = excl;
  if (base + 1 < n) out[base + 1] = excl + v0;
  if (base + 2 < n) out[base + 2] = excl + v0 + v1;
  if (base + 3 < n) out[base + 3] = excl + v0 + v1 + v2;
}
__global__ void scan2_k(int* __restrict__ bsum, int nb) {
  if (threadIdx.x == 0) {
    int acc = 0;
    for (int i = 0; i < nb; ++i) { const int v = bsum[i]; bsum[i] = acc; acc += v; }
  }
}
__global__ void scan3_k(int* __restrict__ out, const int* __restrict__ bsum, int n) {
  const int i = blockIdx.x * blockDim.x + threadIdx.x;
  if (i < n) out[i] += bsum[i >> 10];
}

__global__ void scatter_k(const int* __restrict__ key, const int* __restrict__ other,
                          int* __restrict__ cursor, int* __restrict__ srt, int E) {
  const int e = blockIdx.x * blockDim.x + threadIdx.x;
  if (e < E) {
    const int p = atomicAdd(cursor + key[e], 1);
    srt[p] = other[e];
  }
}

// ======================= CSR-based graph kernels ===========================
// GATv2 aggregate+normalize, wave per dst node.
__global__ void gat_csr_k(const float* __restrict__ fs, const float* __restrict__ fd,
                          const float* __restrict__ attn,
                          const int* __restrict__ rowptr, const int* __restrict__ nbr,
                          float* __restrict__ out, int N) {
  const int lane = threadIdx.x & 63;
  const int wid = (blockIdx.x * blockDim.x + threadIdx.x) >> 6;
  const int nw = (gridDim.x * blockDim.x) >> 6;
  const float aw = attn[lane];
  for (int n = wid; n < N; n += nw) {
    const int beg = rowptr[n], end = rowptr[n + 1];
    const float fdv = fd[(size_t)n * 64 + lane];
    float acc = 0.0f, den = 0.0f;
    int e = beg;
    for (; e + 1 < end; e += 2) {
      const int s0 = nbr[e], s1 = nbr[e + 1];
      const float f0 = fs[(size_t)s0 * 64 + lane];
      const float f1 = fs[(size_t)s1 * 64 + lane];
      float v0 = f0 + fdv; v0 = v0 > 0.0f ? v0 : LRELU_SLOPE * v0;
      float v1 = f1 + fdv; v1 = v1 > 0.0f ? v1 : LRELU_SLOPE * v1;
      float p0 = v0 * aw, p1 = v1 * aw;
#pragma unroll
      for (int o = 32; o; o >>= 1) {
        p0 += __shfl_xor(p0, o, 64);
        p1 += __shfl_xor(p1, o, 64);
      }
      const float e0 = __expf(p0), e1 = __expf(p1);
      den += e0 + e1;
      acc = fmaf(e0, f0, acc);
      acc = fmaf(e1, f1, acc);
    }
    if (e < end) {
      const int s0 = nbr[e];
      const float f0 = fs[(size_t)s0 * 64 + lane];
      float v0 = f0 + fdv; v0 = v0 > 0.0f ? v0 : LRELU_SLOPE * v0;
      float p0 = v0 * aw;
#pragma unroll
      for (int o = 32; o; o >>= 1) p0 += __shfl_xor(p0, o, 64);
      const float e0 = __expf(p0);
      den += e0;
      acc = fmaf(e0, f0, acc);
    }
    const float inv = den > 0.0f ? 1.0f / den : 0.0f;
    out[(size_t)n * 64 + lane] = acc * inv;
  }
}

// h[n] = dinv[n] * sum_e x[nbr_e]*dinv[nbr_e]   (full ahat, wave per node)
__global__ void ahat_csr_k(const float* __restrict__ x, const float* __restrict__ dinv,
                           const int* __restrict__ rowptr, const int* __restrict__ nbr,
                           float* __restrict__ h, int N) {
  const int lane = threadIdx.x & 63;
  const int wid = (blockIdx.x * blockDim.x + threadIdx.x) >> 6;
  const int nw = (gridDim.x * blockDim.x) >> 6;
  for (int n = wid; n < N; n += nw) {
    const int beg = rowptr[n], end = rowptr[n + 1];
    float acc = 0.0f;
    int e = beg;
    for (; e + 1 < end; e += 2) {
      const int s0 = nbr[e], s1 = nbr[e + 1];
      acc = fmaf(x[(size_t)s0 * 64 + lane], dinv[s0], acc);
      acc = fmaf(x[(size_t)s1 * 64 + lane], dinv[s1], acc);
    }
    if (e < end) {
      const int s0 = nbr[e];
      acc = fmaf(x[(size_t)s0 * 64 + lane], dinv[s0], acc);
    }
    h[(size_t)n * 64 + lane] = acc * dinv[n];
  }
}

// dinv[i] = rsqrt(max(deg,1)) from rowptr diff
__global__ void dinv_k(const int* __restrict__ rowptr, float* __restrict__ dinv, int N) {
  const int i = blockIdx.x * blockDim.x + threadIdx.x;
  if (i < N) {
    const float deg = (float)(rowptr[i + 1] - rowptr[i]);
    dinv[i] = rsqrtf(fmaxf(deg, 1.0f));
  }
}

// ---- T1 = -re*h + (re-1)*T0  (h pre-scaled; float4) ----
__global__ void t1_k(const float4* __restrict__ h, const float4* __restrict__ T0,
                     const float* __restrict__ lam, float4* __restrict__ T1, int n4) {
  const float re = 2.0f / lam[0];
  const int stride = gridDim.x * blockDim.x;
  for (int i = blockIdx.x * blockDim.x + threadIdx.x; i < n4; i += stride) {
    const float4 hv = h[i], t0 = T0[i];
    float4 r;
    r.x = -re * hv.x + (re - 1.0f) * t0.x;
    r.y = -re * hv.y + (re - 1.0f) * t0.y;
    r.z = -re * hv.z + (re - 1.0f) * t0.z;
    r.w = -re * hv.w + (re - 1.0f) * t0.w;
    T1[i] = r;
  }
}

// ---- T2 = -2re*h2 + 2(re-1)*T1 - T0  (float4) ----
__global__ void t2_k(const float4* __restrict__ h2, const float4* __restrict__ T1,
                     const float4* __restrict__ T0, const float* __restrict__ lam,
                     float4* __restrict__ T2, int n4) {
  const float re = 2.0f / lam[0];
  const int stride = gridDim.x * blockDim.x;
  for (int i = blockIdx.x * blockDim.x + threadIdx.x; i < n4; i += stride) {
    const float4 hv = h2[i], t1 = T1[i], t0 = T0[i];
    float4 r;
    r.x = -2.0f * re * hv.x + 2.0f * (re - 1.0f) * t1.x - t0.x;
    r.y = -2.0f * re * hv.y + 2.0f * (re - 1.0f) * t1.y - t0.y;
    r.z = -2.0f * re * hv.z + 2.0f * (re - 1.0f) * t1.z - t0.z;
    r.w = -2.0f * re * hv.w + 2.0f * (re - 1.0f) * t1.w - t0.w;
    T2[i] = r;
  }
}

// ---- mutualistic: mP = (p*s)*softmax(p), mS = (p*s)*softmax(s) (wave/row) ----
__global__ void mut_k(const float* __restrict__ hP, const float* __restrict__ hS,
                      float* __restrict__ mP, float* __restrict__ mS, int N) {
  const int lane = threadIdx.x & 63;
  const int u = (blockIdx.x * blockDim.x + threadIdx.x) >> 6;
  if (u >= N) return;
  const float p = hP[(size_t)u * 64 + lane];
  const float s = hS[(size_t)u * 64 + lane];
  const float m = p * s;
  float mxp = p, mxs = s;
#pragma unroll
  for (int o = 32; o; o >>= 1) {
    mxp = fmaxf(mxp, __shfl_xor(mxp, o, 64));
    mxs = fmaxf(mxs, __shfl_xor(mxs, o, 64));
  }
  const float ep = __expf(p - mxp);
  const float es = __expf(s - mxs);
  float sp = ep, ss = es;
#pragma unroll
  for (int o = 32; o; o >>= 1) {
    sp += __shfl_xor(sp, o, 64);
    ss += __shfl_xor(ss, o, 64);
  }
  mP[(size_t)u * 64 + lane] = m * (ep / sp);
  mS[(size_t)u * 64 + lane] = m * (es / ss);
}

// ---- edge dot: out[e] = <A[src[e]], B[dst[e]]> (wave per edge, ILP-2) ----
__global__ void dot_k(const float* __restrict__ A, const float* __restrict__ Bm,
                      const int* __restrict__ src, const int* __restrict__ dst,
                      float* __restrict__ out, int E) {
  const int lane = threadIdx.x & 63;
  const int wid = (blockIdx.x * blockDim.x + threadIdx.x) >> 6;
  const int nw = (gridDim.x * blockDim.x) >> 6;
  for (int e0 = wid * 2; e0 < E; e0 += nw * 2) {
    const bool has1 = (e0 + 1 < E);
    const int s0 = src[e0], d0 = dst[e0];
    const int s1 = has1 ? src[e0 + 1] : s0;
    const int d1 = has1 ? dst[e0 + 1] : d0;
    float p0 = A[(size_t)s0 * 64 + lane] * Bm[(size_t)d0 * 64 + lane];
    float p1 = A[(size_t)s1 * 64 + lane] * Bm[(size_t)d1 * 64 + lane];
#pragma unroll
    for (int o = 32; o; o >>= 1) {
      p0 += __shfl_xor(p0, o, 64);
      p1 += __shfl_xor(p1, o, 64);
    }
    if (lane == 0) {
      out[e0] = p0;
      if (has1) out[e0 + 1] = p1;
    }
  }
}

// ---------------------------------------------------------------------------

static void build_csr(const int* key, const int* other, int E, int N,
                      int* rowptr, int* srt, int* cnt, int* cursor, int* bsum,
                      hipStream_t stream) {
  const int n1 = N + 1;
  hipMemsetAsync(cnt, 0, (size_t)n1 * 4, stream);
  hist_k<<<(E + 255) / 256, 256, 0, stream>>>(key, cnt, E);
  const int nb = (n1 + 1023) / 1024;
  scan1_k<<<nb, 256, 0, stream>>>(cnt, rowptr, bsum, n1);
  scan2_k<<<1, 64, 0, stream>>>(bsum, nb);
  scan3_k<<<(n1 + 255) / 256, 256, 0, stream>>>(rowptr, bsum, n1);
  hipMemcpyAsync(cursor, rowptr, (size_t)N * 4, hipMemcpyDeviceToDevice, stream);
  scatter_k<<<(E + 255) / 256, 256, 0, stream>>>(key, other, cursor, srt, E);
}

static void run_gat(const float* hsrc, int Ns, const float* hdst, int Nd,
                    const float* Wsrc, const float* bsrc,
                    const float* Wdst, const float* bdst, const float* attn,
                    const int* rowptr, const int* nbr,
                    float* fs, float* fd, float* out, hipStream_t stream) {
  gemm_rowlane_k<1><<<gemm_grid(Ns), 256, 0, stream>>>(hsrc, nullptr, nullptr, Wsrc, bsrc, fs, Ns);
  gemm_rowlane_k<1><<<gemm_grid(Nd), 256, 0, stream>>>(hdst, nullptr, nullptr, Wdst, bdst, fd, Nd);
  gat_csr_k<<<EDGE_BLOCKS, 256, 0, stream>>>(fs, fd, attn, rowptr, nbr, out, Nd);
}

extern "C" void kernel_launch(void* const* d_in, const int* in_sizes, int n_in,
                              void* d_out, int out_size, void* d_ws, size_t ws_size,
                              hipStream_t stream) {
  const float* user_emb = (const float*)d_in[0];
  const float* item_emb = (const float*)d_in[1];
  const int* rate_src = (const int*)d_in[2];
  const int* rate_dst = (const int*)d_in[3];
  const int* link_src = (const int*)d_in[4];
  const int* link_dst = (const int*)d_in[5];
  const int* neg_rate_src = (const int*)d_in[6];
  const int* neg_rate_dst = (const int*)d_in[7];
  const int* neg_link_src = (const int*)d_in[8];
  const int* neg_link_dst = (const int*)d_in[9];
  const float* lam = (const float*)d_in[10];
  const float* gat_Wsrc = (const float*)d_in[11];
  const float* gat_bsrc = (const float*)d_in[12];
  const float* gat_Wdst = (const float*)d_in[13];
  const float* gat_bdst = (const float*)d_in[14];
  const float* gat_attn = (const float*)d_in[15];
  const float* W_out = (const float*)d_in[16];
  const float* b_out = (const float*)d_in[17];
  const float* cheb_W = (const float*)d_in[18];
  const float* cheb_b = (const float*)d_in[19];
  const float* Wc = (const float*)d_in[20];
  const float* bc = (const float*)d_in[21];
  const float* Wsm = (const float*)d_in[22];
  const float* bs = (const float*)d_in[23];
  const float* WpP = (const float*)d_in[24];
  const float* bpP = (const float*)d_in[25];
  const float* WpS = (const float*)d_in[26];
  const float* bpS = (const float*)d_in[27];

  const int NU = in_sizes[0] / 64;
  const int NI = in_sizes[1] / 64;
  const int NR = in_sizes[2];
  const int NL = in_sizes[4];
  const int NMAX = NU > NI ? NU : NI;
  const size_t MAT = (size_t)NMAX * 64;

  float* ws = (float*)d_ws;
  float* B0 = ws + 0 * MAT;  // fs scratch / cheb h_hat
  float* B1 = ws + 1 * MAT;  // fd scratch
  float* B2 = ws + 2 * MAT;  // h1_item -> T1 -> user_social -> h_mS
  float* B3 = ws + 3 * MAT;  // h2_user -> T2 -> h_mP
  float* B4 = ws + 4 * MAT;  // item_infl -> h_uP
  float* B5 = ws + 5 * MAT;  // social_item -> h_uS
  float* B6 = ws + 6 * MAT;  // user_pref -> h_new_P
  float* B7 = ws + 7 * MAT;  // rst -> h_new_S
  // int scratch after 8 float buffers
  int* ip = (int*)(ws + 8 * MAT);
  int* rp_rd = ip;                 // NI+1  (rate grouped by dst=item)
  int* rp_rs = rp_rd + (NI + 1);   // NU+1  (rate grouped by src=user)
  int* rp_ld = rp_rs + (NU + 1);   // NU+1  (link grouped by dst=user)
  int* srt_rd = rp_ld + (NU + 1);  // NR    (rate_src sorted by rate_dst)
  int* srt_rs = srt_rd + NR;       // NR    (rate_dst sorted by rate_src)
  int* srt_ld = srt_rs + NR;       // NL    (link_src sorted by link_dst)
  int* cnt = srt_ld + NL;          // NMAX+1 (sort scratch)
  int* cursor = cnt + (NMAX + 1);  // NMAX
  int* bsum = cursor + NMAX;       // 256
  float* dinv = (float*)(bsum + 256);  // NU

  const int W64 = 64 * 64, B64 = 64;

  // ---- build the 3 CSR groupings (reused by 5 GATs + cheb + indeg) ----
  build_csr(rate_dst, rate_src, NR, NI, rp_rd, srt_rd, cnt, cursor, bsum, stream);
  build_csr(rate_src, rate_dst, NR, NU, rp_rs, srt_rs, cnt, cursor, bsum, stream);
  build_csr(link_dst, link_src, NL, NU, rp_ld, srt_ld, cnt, cursor, bsum, stream);

  // ---- gat0: user -> item over rate edges -> B2 (h1_item, normalized) ----
  run_gat(user_emb, NU, item_emb, NI,
          gat_Wsrc + 0 * W64, gat_bsrc + 0 * B64, gat_Wdst + 0 * W64,
          gat_bdst + 0 * B64, gat_attn + 0 * B64,
          rp_rd, srt_rd, B0, B1, B2, stream);
  // ---- gat1: item -> user (reverse rate) -> B3 (h2_user) ----
  run_gat(item_emb, NI, user_emb, NU,
          gat_Wsrc + 1 * W64, gat_bsrc + 1 * B64, gat_Wdst + 1 * W64,
          gat_bdst + 1 * B64, gat_attn + 1 * B64,
          rp_rs, srt_rs, B0, B1, B3, stream);
  // ---- gat2: h1_item -> user -> B4 (item_infl) ----
  run_gat(B2, NI, user_emb, NU,
          gat_Wsrc + 2 * W64, gat_bsrc + 2 * B64, gat_Wdst + 2 * W64,
          gat_bdst + 2 * B64, gat_attn + 2 * B64,
          rp_rs, srt_rs, B0, B1, B4, stream);
  // ---- gat3: h2_user -> user over link edges -> B5 (social_item) ----
  run_gat(B3, NU, user_emb, NU,
          gat_Wsrc + 3 * W64, gat_bsrc + 3 * B64, gat_Wdst + 3 * W64,
          gat_bdst + 3 * B64, gat_attn + 3 * B64,
          rp_ld, srt_ld, B0, B1, B5, stream);
  // ---- user_pref = [item_infl, social_item] @ W_out + b_out -> B6 ----
  gemm_rowlane_k<2><<<gemm_grid(NU), 256, 0, stream>>>(B4, B5, nullptr, W_out, b_out, B6, NU);

  // ---- ChebConv(k=3) on link graph ----
  dinv_k<<<(NU + 255) / 256, 256, 0, stream>>>(rp_ld, dinv, NU);
  const int TOT = NU * 64;
  ahat_csr_k<<<EDGE_BLOCKS, 256, 0, stream>>>(user_emb, dinv, rp_ld, srt_ld, B0, NU);
  t1_k<<<EDGE_BLOCKS, 256, 0, stream>>>((const float4*)B0, (const float4*)user_emb,
                                        lam, (float4*)B2, TOT / 4);
  ahat_csr_k<<<EDGE_BLOCKS, 256, 0, stream>>>(B2, dinv, rp_ld, srt_ld, B0, NU);
  t2_k<<<EDGE_BLOCKS, 256, 0, stream>>>((const float4*)B0, (const float4*)B2,
                                        (const float4*)user_emb, lam, (float4*)B3, TOT / 4);
  // rst = T0@W0 + T1@W1 + T2@W2 + b -> B7
  gemm_rowlane_k<3><<<gemm_grid(NU), 256, 0, stream>>>(user_emb, B2, B3, cheb_W, cheb_b, B7, NU);

  // ---- gat4: rst -> rst over link edges -> B2 (user_social) ----
  run_gat(B7, NU, B7, NU,
          gat_Wsrc + 4 * W64, gat_bsrc + 4 * B64, gat_Wdst + 4 * W64,
          gat_bdst + 4 * B64, gat_attn + 4 * B64,
          rp_ld, srt_ld, B0, B1, B2, stream);

  // ---- mutualistic ----
  gemm_rowlane_k<2><<<gemm_grid(NU), 256, 0, stream>>>(B6, user_emb, nullptr, Wc, bc, B4, NU);  // h_uP
  gemm_rowlane_k<2><<<gemm_grid(NU), 256, 0, stream>>>(B2, user_emb, nullptr, Wsm, bs, B5, NU); // h_uS
  mut_k<<<(NU + 3) / 4, 256, 0, stream>>>(B4, B5, B3, B2, NU);  // mP->B3, mS->B2
  gemm_rowlane_k<2><<<gemm_grid(NU), 256, 0, stream>>>(B3, B4, nullptr, WpP, bpP, B6, NU);  // h_new_P
  gemm_rowlane_k<2><<<gemm_grid(NU), 256, 0, stream>>>(B2, B5, nullptr, WpS, bpS, B7, NU);  // h_new_S

  // ---- predictors ----
  float* out = (float*)d_out;
  dot_k<<<EDGE_BLOCKS, 256, 0, stream>>>(B6, item_emb, rate_src, rate_dst, out, NR);
  dot_k<<<EDGE_BLOCKS, 256, 0, stream>>>(B6, item_emb, neg_rate_src, neg_rate_dst, out + NR, NR);
  dot_k<<<EDGE_BLOCKS, 256, 0, stream>>>(B7, user_emb, link_src, link_dst, out + 2 * (size_t)NR, NL);
  dot_k<<<EDGE_BLOCKS, 256, 0, stream>>>(B7, user_emb, neg_link_src, neg_link_dst, out + 2 * (size_t)NR + NL, NL);
}